// Round 4
// baseline (19873.894 us; speedup 1.0000x reference)
//
#include <hip/hip_runtime.h>
#include <stdint.h>
#include <math.h>

#define NB 512
#define NS 200
#define NH 128
#define NH3 384
#define NBLK 256   // blocks; each handles rows b and b+NBLK

// ---------------- XLA-exact scalar helpers ----------------
__device__ __forceinline__ float xla_tanhf(float x) {
  float cx = fminf(fmaxf(x, -9.0f), 9.0f);
  float x2 = __fmul_rn(cx, cx);
  float p = -2.76076847742355e-16f;
  p = __fadd_rn(__fmul_rn(x2, p), 2.00018790482477e-13f);
  p = __fadd_rn(__fmul_rn(x2, p), -8.60467152213735e-11f);
  p = __fadd_rn(__fmul_rn(x2, p), 5.12229709037114e-08f);
  p = __fadd_rn(__fmul_rn(x2, p), 1.48572235717979e-05f);
  p = __fadd_rn(__fmul_rn(x2, p), 6.37261928875436e-04f);
  p = __fadd_rn(__fmul_rn(x2, p), 4.89352455891786e-03f);
  p = __fmul_rn(cx, p);
  float q = 1.19825839466702e-06f;
  q = __fadd_rn(__fmul_rn(x2, q), 1.18534705686654e-04f);
  q = __fadd_rn(__fmul_rn(x2, q), 2.26843463243900e-03f);
  q = __fadd_rn(__fmul_rn(x2, q), 4.89352518554385e-03f);
  float r = __fdiv_rn(p, q);
  return (fabsf(x) < 0.0004f) ? x : r;
}

__device__ __forceinline__ float xla_sigmoidf(float x) {
  return __fadd_rn(0.5f, __fmul_rn(0.5f, xla_tanhf(__fmul_rn(0.5f, x))));
}

__device__ __forceinline__ uint32_t rotl32(uint32_t v, int r) {
  return (v << r) | (v >> (32 - r));
}
__device__ __forceinline__ void threefry2x32(uint32_t k0, uint32_t k1,
                                             uint32_t x0, uint32_t x1,
                                             uint32_t& o0, uint32_t& o1) {
  uint32_t k2 = k0 ^ k1 ^ 0x1BD11BDAu;
  x0 += k0; x1 += k1;
  #define TFR(r) { x0 += x1; x1 = rotl32(x1, r); x1 ^= x0; }
  TFR(13) TFR(15) TFR(26) TFR(6)
  x0 += k1; x1 += k2 + 1u;
  TFR(17) TFR(29) TFR(16) TFR(24)
  x0 += k2; x1 += k0 + 2u;
  TFR(13) TFR(15) TFR(26) TFR(6)
  x0 += k0; x1 += k1 + 3u;
  TFR(17) TFR(29) TFR(16) TFR(24)
  x0 += k1; x1 += k2 + 4u;
  TFR(13) TFR(15) TFR(26) TFR(6)
  x0 += k2; x1 += k0 + 5u;
  #undef TFR
  o0 = x0; o1 = x1;
}

__device__ __forceinline__ float bits_to_gumbel(uint32_t bits) {
  const float kTiny = 1.1754943508222875e-38f;
  float f = __fsub_rn(__uint_as_float((bits >> 9) | 0x3F800000u), 1.0f);
  float u = __fadd_rn(__fmul_rn(f, __fsub_rn(1.0f, kTiny)), kTiny);
  u = fmaxf(kTiny, u);
  return -logf(-logf(u));
}

// ---------------- persistent whole-decode kernel: 2 batch rows / block ----
__global__ __launch_bounds__(256, 1) void k_decode(
    const float* __restrict__ stat, const float* __restrict__ dyn,
    const float* __restrict__ sW,   const float* __restrict__ sb,
    const float* __restrict__ dW,   const float* __restrict__ db,
    const float* __restrict__ x0,   const float* __restrict__ h0,
    const float* __restrict__ Wemb, const float* __restrict__ bemb,
    const float* __restrict__ Wih,  const float* __restrict__ Whh,
    const float* __restrict__ bih,  const float* __restrict__ bhh,
    const float* __restrict__ Wa,   const float* __restrict__ va,
    const float* __restrict__ Wd,   const float* __restrict__ vd,
    float* __restrict__ out) {

  __shared__ float WaHT[NH][130];          // Wa[:,256+k] transposed
  __shared__ __align__(16) float st0A[NS], st1A[NS], dy0A[NS], dy1A[NS];
  __shared__ __align__(16) float st0B[NS], st1B[NS], dy0B[NS], dy1B[NS];
  __shared__ float4 AF4[NH];               // {As0,As1,Ad0,Ad1}
  __shared__ float2 AF2[NH];               // {Ac, va}
  __shared__ float4 DF4[NH];               // {Ds0,Ds1,Dc,vd}
  __shared__ float Cw0[NH], Cw1[NH], Cwb[NH];
  __shared__ float WembL[2*NH], bembL[NH];
  __shared__ float bihL[NH3], bhhL[NH3];
  __shared__ __align__(16) float embA[NH], embB[NH], hA[NH], hB[NH];
  __shared__ float giA[NH3], ghA[NH3], giB[NH3], ghB[NH3];
  __shared__ float2 HtAB[NH];              // Hterm (reused as Cterm)
  __shared__ float ex2A[NS], ex2B[NS];
  __shared__ uint32_t keysL[2*NS];
  __shared__ float xpA[2], xpB[2];
  __shared__ float part[4][16];
  __shared__ int   partI[4][2];

  const int t = threadIdx.x;
  const int w = t >> 6;
  const int bA = blockIdx.x;
  const int bB = blockIdx.x + NBLK;

  // ---- one-time setup ----
  // register-resident GRU weight rows (shared by both batch rows):
  // thread t owns dot rows: d0 = Wih[t]; d1 = (t<128 ? Wih[256+t] : Whh[t-128]);
  // d2 = Whh[t+128].
  float4 w0[32], w1[32], w2[32];
  {
    const float4* p0 = (const float4*)(Wih + (size_t)t * NH);
    const float4* p1 = (t < NH)
        ? (const float4*)(Wih + (size_t)(256 + t) * NH)
        : (const float4*)(Whh + (size_t)(t - NH) * NH);
    const float4* p2 = (const float4*)(Whh + (size_t)(t + NH) * NH);
    #pragma unroll
    for (int k4 = 0; k4 < 32; ++k4) { w0[k4] = p0[k4]; w1[k4] = p1[k4]; w2[k4] = p2[k4]; }
  }

  if (t < NS) {
    st0A[t] = stat[(size_t)bA*2*NS + t];
    st1A[t] = stat[(size_t)bA*2*NS + NS + t];
    dy0A[t] = dyn[(size_t)bA*2*NS + t];
    dy1A[t] = dyn[(size_t)bA*2*NS + NS + t];
    st0B[t] = stat[(size_t)bB*2*NS + t];
    st1B[t] = stat[(size_t)bB*2*NS + NS + t];
    dy0B[t] = dyn[(size_t)bB*2*NS + t];
    dy1B[t] = dyn[(size_t)bB*2*NS + NS + t];
    uint32_t q0, q1;
    threefry2x32(0u, 42u, 0u, (uint32_t)t, q0, q1);
    keysL[2*t] = q0; keysL[2*t + 1] = q1;
  }
  // folded attention/decoder vectors (identical math to round-3)
  if (t < NH) {
    int h = t;
    const float* war = Wa + (size_t)h * NH3;
    float as0 = 0.f, as1 = 0.f, ad0 = 0.f, ad1 = 0.f, ac = 0.f;
    for (int k = 0; k < NH; ++k) {
      as0 = fmaf(war[k],     sW[k*2+0], as0);
      as1 = fmaf(war[k],     sW[k*2+1], as1);
      ad0 = fmaf(war[NH+k],  dW[k*2+0], ad0);
      ad1 = fmaf(war[NH+k],  dW[k*2+1], ad1);
      ac  = fmaf(war[k],     sb[k],     ac);
    }
    for (int k = 0; k < NH; ++k) ac = fmaf(war[NH+k], db[k], ac);
    AF4[h] = make_float4(as0, as1, ad0, ad1);
    AF2[h] = make_float2(ac, va[h]);

    const float* wdr = Wd + (size_t)h * 256;
    float ds0 = 0.f, ds1 = 0.f, dc = 0.f, c0 = 0.f, c1 = 0.f, cb = 0.f;
    for (int k = 0; k < NH; ++k) {
      ds0 = fmaf(wdr[k],    sW[k*2+0], ds0);
      ds1 = fmaf(wdr[k],    sW[k*2+1], ds1);
      dc  = fmaf(wdr[k],    sb[k],     dc);
      c0  = fmaf(wdr[NH+k], sW[k*2+0], c0);
      c1  = fmaf(wdr[NH+k], sW[k*2+1], c1);
      cb  = fmaf(wdr[NH+k], sb[k],     cb);
    }
    DF4[h] = make_float4(ds0, ds1, dc, vd[h]);
    Cw0[h] = c0;  Cw1[h] = c1;  Cwb[h] = cb;

    bembL[h] = bemb[h];
    WembL[2*h]   = Wemb[2*h];
    WembL[2*h+1] = Wemb[2*h+1];
    hA[h] = h0[h];
    hB[h] = h0[h];
  }
  for (int i = t; i < NH3; i += 256) { bihL[i] = bih[i]; bhhL[i] = bhh[i]; }
  for (int i = t; i < NH*NH; i += 256) {
    int k = i >> 7, h = i & 127;
    WaHT[k][h] = Wa[(size_t)h*NH3 + 2*NH + k];
  }
  if (t == 0) { xpA[0] = x0[0]; xpA[1] = x0[1]; xpB[0] = x0[0]; xpB[1] = x0[1]; }
  __syncthreads();

  // ---- 200 decode steps ----
  for (int step = 0; step < NS; ++step) {
    // S0: emb = x @ Wemb^T + bemb  (t<128: row A; t>=128: row B)
    if (t < NH) {
      float e = fmaf(xpA[1], WembL[t*2+1], __fmul_rn(xpA[0], WembL[t*2+0]));
      embA[t] = __fadd_rn(e, bembL[t]);
    } else {
      int h = t - NH;
      float e = fmaf(xpB[1], WembL[h*2+1], __fmul_rn(xpB[0], WembL[h*2+0]));
      embB[h] = __fadd_rn(e, bembL[h]);
    }
    __syncthreads();

    // S1: GRU dots for BOTH rows (exact sequential-k single-acc per dot)
    {
      const float4* e4A = (const float4*)embA;
      const float4* h4A = (const float4*)hA;
      const float4* e4B = (const float4*)embB;
      const float4* h4B = (const float4*)hB;
      float a0A = 0.f, a1A = 0.f, a2A = 0.f;
      float a0B = 0.f, a1B = 0.f, a2B = 0.f;
      #define GRU_DOT2(SA, SB)                                              \
        _Pragma("unroll")                                                   \
        for (int k4 = 0; k4 < 32; ++k4) {                                   \
          float4 evA = e4A[k4], hvA = h4A[k4];                              \
          float4 evB = e4B[k4], hvB = h4B[k4];                              \
          float4 sA = SA, sB = SB;                                          \
          float4 c0 = w0[k4], c1 = w1[k4], c2 = w2[k4];                     \
          a0A = fmaf(c0.x, evA.x, a0A); a0A = fmaf(c0.y, evA.y, a0A);       \
          a0A = fmaf(c0.z, evA.z, a0A); a0A = fmaf(c0.w, evA.w, a0A);       \
          a0B = fmaf(c0.x, evB.x, a0B); a0B = fmaf(c0.y, evB.y, a0B);       \
          a0B = fmaf(c0.z, evB.z, a0B); a0B = fmaf(c0.w, evB.w, a0B);       \
          a1A = fmaf(c1.x, sA.x, a1A);  a1A = fmaf(c1.y, sA.y, a1A);        \
          a1A = fmaf(c1.z, sA.z, a1A);  a1A = fmaf(c1.w, sA.w, a1A);        \
          a1B = fmaf(c1.x, sB.x, a1B);  a1B = fmaf(c1.y, sB.y, a1B);        \
          a1B = fmaf(c1.z, sB.z, a1B);  a1B = fmaf(c1.w, sB.w, a1B);        \
          a2A = fmaf(c2.x, hvA.x, a2A); a2A = fmaf(c2.y, hvA.y, a2A);       \
          a2A = fmaf(c2.z, hvA.z, a2A); a2A = fmaf(c2.w, hvA.w, a2A);       \
          a2B = fmaf(c2.x, hvB.x, a2B); a2B = fmaf(c2.y, hvB.y, a2B);       \
          a2B = fmaf(c2.z, hvB.z, a2B); a2B = fmaf(c2.w, hvB.w, a2B);       \
        }
      if (t < NH) { GRU_DOT2(evA, evB) } else { GRU_DOT2(hvA, hvB) }
      #undef GRU_DOT2
      giA[t] = __fadd_rn(a0A, bihL[t]);
      giB[t] = __fadd_rn(a0B, bihL[t]);
      if (t < NH) {
        giA[256 + t] = __fadd_rn(a1A, bihL[256 + t]);
        giB[256 + t] = __fadd_rn(a1B, bihL[256 + t]);
      } else {
        ghA[t - NH] = __fadd_rn(a1A, bhhL[t - NH]);
        ghB[t - NH] = __fadd_rn(a1B, bhhL[t - NH]);
      }
      ghA[t + NH] = __fadd_rn(a2A, bhhL[t + NH]);
      ghB[t + NH] = __fadd_rn(a2B, bhhL[t + NH]);
    }
    __syncthreads();

    // S2: gates (torch r,z,n), h_new (in place)
    if (t < NH) {
      float r = xla_sigmoidf(__fadd_rn(giA[t],      ghA[t]));
      float z = xla_sigmoidf(__fadd_rn(giA[t+NH],   ghA[t+NH]));
      float n = xla_tanhf(__fadd_rn(giA[t+2*NH], __fmul_rn(r, ghA[t+2*NH])));
      float hv = hA[t];
      hA[t] = __fadd_rn(__fmul_rn(__fsub_rn(1.0f, z), n), __fmul_rn(z, hv));
    } else {
      int h = t - NH;
      float r = xla_sigmoidf(__fadd_rn(giB[h],      ghB[h]));
      float z = xla_sigmoidf(__fadd_rn(giB[h+NH],   ghB[h+NH]));
      float n = xla_tanhf(__fadd_rn(giB[h+2*NH], __fmul_rn(r, ghB[h+2*NH])));
      float hv = hB[h];
      hB[h] = __fadd_rn(__fmul_rn(__fsub_rn(1.0f, z), n), __fmul_rn(z, hv));
    }
    __syncthreads();

    // S3: Hterm = Wa[:,256:384] @ h_new (ascending-k single acc)
    if (t < NH) {
      float acc = 0.f;
      #pragma unroll 8
      for (int k = 0; k < NH; ++k) acc = fmaf(WaHT[k][t], hA[k], acc);
      HtAB[t].x = acc;
    } else {
      int h = t - NH;
      float acc = 0.f;
      #pragma unroll 8
      for (int k = 0; k < NH; ++k) acc = fmaf(WaHT[k][h], hB[k], acc);
      HtAB[h].y = acc;
    }
    __syncthreads();

    // S4: attention scores, both rows per lane
    float scA = -INFINITY, scB = -INFINITY;
    if (t < NS) {
      float s0A = st0A[t], s1A = st1A[t], d0A = dy0A[t], d1A = dy1A[t];
      float s0B = st0B[t], s1B = st1B[t], d0B = dy0B[t], d1B = dy1B[t];
      float accA = 0.f, accB = 0.f;
      #pragma unroll 2
      for (int h = 0; h < NH; ++h) {
        float4 af = AF4[h]; float2 a2 = AF2[h]; float2 ht = HtAB[h];
        float eA = fmaf(af.y, s1A, __fmul_rn(af.x, s0A));
        eA = fmaf(af.z, d0A, eA);
        eA = fmaf(af.w, d1A, eA);
        eA = __fadd_rn(eA, a2.x);
        eA = __fadd_rn(eA, ht.x);
        accA = fmaf(a2.y, xla_tanhf(eA), accA);
        float eB = fmaf(af.y, s1B, __fmul_rn(af.x, s0B));
        eB = fmaf(af.z, d0B, eB);
        eB = fmaf(af.w, d1B, eB);
        eB = __fadd_rn(eB, a2.x);
        eB = __fadd_rn(eB, ht.y);
        accB = fmaf(a2.y, xla_tanhf(eB), accB);
      }
      scA = accA; scB = accB;
    }

    // attn max (exact: order-independent)
    {
      float mA = scA, mB = scB;
      #pragma unroll
      for (int m = 1; m < 64; m <<= 1) {
        mA = fmaxf(mA, __shfl_xor(mA, m));
        mB = fmaxf(mB, __shfl_xor(mB, m));
      }
      if ((t & 63) == 0) { part[w][0] = mA; part[w][1] = mB; }
    }
    __syncthreads();
    float mA = fmaxf(fmaxf(part[0][0], part[1][0]), fmaxf(part[2][0], part[3][0]));
    float mB = fmaxf(fmaxf(part[0][1], part[1][1]), fmaxf(part[2][1], part[3][1]));

    // exp + sum
    float exA = 0.f, exB = 0.f;
    if (t < NS) {
      exA = expf(__fsub_rn(scA, mA));
      exB = expf(__fsub_rn(scB, mB));
    }
    {
      float sA = exA, sB = exB;
      #pragma unroll
      for (int m = 1; m < 64; m <<= 1) {
        sA = __fadd_rn(sA, __shfl_xor(sA, m));
        sB = __fadd_rn(sB, __shfl_xor(sB, m));
      }
      if ((t & 63) == 0) { part[w][2] = sA; part[w][3] = sB; }
    }
    __syncthreads();
    float sumeA = __fadd_rn(__fadd_rn(__fadd_rn(part[0][2], part[1][2]), part[2][2]), part[3][2]);
    float sumeB = __fadd_rn(__fadd_rn(__fadd_rn(part[0][3], part[1][3]), part[2][3]), part[3][3]);

    // context sums: Σ ex·st0, Σ ex·st1 per row (normalize at the end)
    {
      float c0A = 0.f, c1A = 0.f, c0B = 0.f, c1B = 0.f;
      if (t < NS) {
        c0A = __fmul_rn(exA, st0A[t]); c1A = __fmul_rn(exA, st1A[t]);
        c0B = __fmul_rn(exB, st0B[t]); c1B = __fmul_rn(exB, st1B[t]);
      }
      #pragma unroll
      for (int m = 1; m < 64; m <<= 1) {
        c0A = __fadd_rn(c0A, __shfl_xor(c0A, m));
        c1A = __fadd_rn(c1A, __shfl_xor(c1A, m));
        c0B = __fadd_rn(c0B, __shfl_xor(c0B, m));
        c1B = __fadd_rn(c1B, __shfl_xor(c1B, m));
      }
      if ((t & 63) == 0) {
        part[w][4] = c0A; part[w][5] = c1A; part[w][6] = c0B; part[w][7] = c1B;
      }
    }
    __syncthreads();

    // Cterm (reuse HtAB): Ct = R0*Cw0 + R1*Cw1 + Cwb   (Σattn ≡ 1)
    if (t < NH) {
      float r0 = __fadd_rn(__fadd_rn(__fadd_rn(part[0][4], part[1][4]), part[2][4]), part[3][4]);
      float r1 = __fadd_rn(__fadd_rn(__fadd_rn(part[0][5], part[1][5]), part[2][5]), part[3][5]);
      r0 = __fdiv_rn(r0, sumeA); r1 = __fdiv_rn(r1, sumeA);
      HtAB[t].x = fmaf(r0, Cw0[t], fmaf(r1, Cw1[t], Cwb[t]));
    } else {
      int h = t - NH;
      float r0 = __fadd_rn(__fadd_rn(__fadd_rn(part[0][6], part[1][6]), part[2][6]), part[3][6]);
      float r1 = __fadd_rn(__fadd_rn(__fadd_rn(part[0][7], part[1][7]), part[2][7]), part[3][7]);
      r0 = __fdiv_rn(r0, sumeB); r1 = __fdiv_rn(r1, sumeB);
      HtAB[h].y = fmaf(r0, Cw0[h], fmaf(r1, Cw1[h], Cwb[h]));
    }
    __syncthreads();

    // S5: decoder logits, both rows per lane
    float sc2A = -INFINITY, sc2B = -INFINITY;
    if (t < NS) {
      float s0A = st0A[t], s1A = st1A[t];
      float s0B = st0B[t], s1B = st1B[t];
      float accA = 0.f, accB = 0.f;
      #pragma unroll 2
      for (int h = 0; h < NH; ++h) {
        float4 df = DF4[h]; float2 ct = HtAB[h];
        float dA = fmaf(df.y, s1A, __fmul_rn(df.x, s0A));
        dA = __fadd_rn(dA, df.z);
        dA = __fadd_rn(dA, ct.x);
        accA = fmaf(df.w, xla_tanhf(dA), accA);
        float dB = fmaf(df.y, s1B, __fmul_rn(df.x, s0B));
        dB = __fadd_rn(dB, df.z);
        dB = __fadd_rn(dB, ct.y);
        accB = fmaf(df.w, xla_tanhf(dB), accB);
      }
      sc2A = accA; sc2B = accB;
    }

    // decoder max
    {
      float qA = sc2A, qB = sc2B;
      #pragma unroll
      for (int m = 1; m < 64; m <<= 1) {
        qA = fmaxf(qA, __shfl_xor(qA, m));
        qB = fmaxf(qB, __shfl_xor(qB, m));
      }
      if ((t & 63) == 0) { part[w][8] = qA; part[w][9] = qB; }
    }
    __syncthreads();
    float m2A = fmaxf(fmaxf(part[0][8], part[1][8]), fmaxf(part[2][8], part[3][8]));
    float m2B = fmaxf(fmaxf(part[0][9], part[1][9]), fmaxf(part[2][9], part[3][9]));

    // decoder exp + sum (ex stored to LDS for winner prob lookup)
    float e2A = 0.f, e2B = 0.f;
    if (t < NS) {
      e2A = expf(__fsub_rn(sc2A, m2A));
      e2B = expf(__fsub_rn(sc2B, m2B));
      ex2A[t] = e2A; ex2B[t] = e2B;
    }
    {
      float sA = e2A, sB = e2B;
      #pragma unroll
      for (int m = 1; m < 64; m <<= 1) {
        sA = __fadd_rn(sA, __shfl_xor(sA, m));
        sB = __fadd_rn(sB, __shfl_xor(sB, m));
      }
      if ((t & 63) == 0) { part[w][10] = sA; part[w][11] = sB; }
    }
    __syncthreads();
    float sume2A = __fadd_rn(__fadd_rn(__fadd_rn(part[0][10], part[1][10]), part[2][10]), part[3][10]);
    float sume2B = __fadd_rn(__fadd_rn(__fadd_rn(part[0][11], part[1][11]), part[2][11]), part[3][11]);

    // gumbel-max sampling (bit-exact threefry; first-index tiebreak)
    uint32_t k0 = keysL[2*step], k1 = keysL[2*step + 1];
    float gvA = -INFINITY, gvB = -INFINITY;
    int iA = t, iB = t;
    if (t < NS) {
      uint32_t q0, q1;
      threefry2x32(k0, k1, 0u, (uint32_t)(bA*NS + t), q0, q1);
      gvA = __fadd_rn(bits_to_gumbel(q0 ^ q1), sc2A);
      threefry2x32(k0, k1, 0u, (uint32_t)(bB*NS + t), q0, q1);
      gvB = __fadd_rn(bits_to_gumbel(q0 ^ q1), sc2B);
    }
    #pragma unroll
    for (int m = 1; m < 64; m <<= 1) {
      float ovA = __shfl_xor(gvA, m); int oiA = __shfl_xor(iA, m);
      if (ovA > gvA || (ovA == gvA && oiA < iA)) { gvA = ovA; iA = oiA; }
      float ovB = __shfl_xor(gvB, m); int oiB = __shfl_xor(iB, m);
      if (ovB > gvB || (ovB == gvB && oiB < iB)) { gvB = ovB; iB = oiB; }
    }
    if ((t & 63) == 0) {
      part[w][12] = gvA; part[w][13] = gvB;
      partI[w][0] = iA;  partI[w][1] = iB;
    }
    __syncthreads();

    if (t == 0) {
      float bv = part[0][12]; int bi = partI[0][0];
      #pragma unroll
      for (int ww = 1; ww < 4; ++ww) {
        float v2 = part[ww][12]; int i2 = partI[ww][0];
        if (v2 > bv || (v2 == bv && i2 < bi)) { bv = v2; bi = i2; }
      }
      out[(size_t)bA*NS + step] = (float)bi;
      out[(size_t)NB*NS + (size_t)bA*NS + step] = __fdiv_rn(ex2A[bi], sume2A);
      xpA[0] = st0A[bi]; xpA[1] = st1A[bi];
    } else if (t == 128) {
      float bv = part[0][13]; int bi = partI[0][1];
      #pragma unroll
      for (int ww = 1; ww < 4; ++ww) {
        float v2 = part[ww][13]; int i2 = partI[ww][1];
        if (v2 > bv || (v2 == bv && i2 < bi)) { bv = v2; bi = i2; }
      }
      out[(size_t)bB*NS + step] = (float)bi;
      out[(size_t)NB*NS + (size_t)bB*NS + step] = __fdiv_rn(ex2B[bi], sume2B);
      xpB[0] = st0B[bi]; xpB[1] = st1B[bi];
    }
    __syncthreads();
  }
}

// ---------------- host launch ----------------
extern "C" void kernel_launch(void* const* d_in, const int* in_sizes, int n_in,
                              void* d_out, int out_size, void* d_ws, size_t ws_size,
                              hipStream_t stream) {
  (void)in_sizes; (void)n_in; (void)out_size; (void)d_ws; (void)ws_size;
  const float* stat = (const float*)d_in[0];
  const float* dyn  = (const float*)d_in[1];
  const float* sW   = (const float*)d_in[2];
  const float* sb   = (const float*)d_in[3];
  const float* dW   = (const float*)d_in[4];
  const float* db   = (const float*)d_in[5];
  const float* x0   = (const float*)d_in[6];
  const float* h0   = (const float*)d_in[7];
  const float* Wemb = (const float*)d_in[8];
  const float* bemb = (const float*)d_in[9];
  const float* Wih  = (const float*)d_in[10];
  const float* Whh  = (const float*)d_in[11];
  const float* bih  = (const float*)d_in[12];
  const float* bhh  = (const float*)d_in[13];
  const float* Wa   = (const float*)d_in[14];
  const float* va   = (const float*)d_in[15];
  const float* Wd   = (const float*)d_in[16];
  const float* vd   = (const float*)d_in[17];
  float* out = (float*)d_out;

  k_decode<<<NBLK, 256, 0, stream>>>(stat, dyn, sW, sb, dW, db, x0, h0,
                                     Wemb, bemb, Wih, Whh, bih, bhh,
                                     Wa, va, Wd, vd, out);
}

// Round 5
// 8862.698 us; speedup vs baseline: 2.2424x; 2.2424x over previous
//
#include <hip/hip_runtime.h>
#include <stdint.h>
#include <math.h>

#define NB 512
#define NS 200
#define NH 128
#define NH3 384
#define NBLK 256   // blocks; block handles rows b and b+NBLK

// ---------------- XLA-exact scalar helpers ----------------
__device__ __forceinline__ float xla_tanhf(float x) {
  float cx = fminf(fmaxf(x, -9.0f), 9.0f);
  float x2 = __fmul_rn(cx, cx);
  float p = -2.76076847742355e-16f;
  p = __fadd_rn(__fmul_rn(x2, p), 2.00018790482477e-13f);
  p = __fadd_rn(__fmul_rn(x2, p), -8.60467152213735e-11f);
  p = __fadd_rn(__fmul_rn(x2, p), 5.12229709037114e-08f);
  p = __fadd_rn(__fmul_rn(x2, p), 1.48572235717979e-05f);
  p = __fadd_rn(__fmul_rn(x2, p), 6.37261928875436e-04f);
  p = __fadd_rn(__fmul_rn(x2, p), 4.89352455891786e-03f);
  p = __fmul_rn(cx, p);
  float q = 1.19825839466702e-06f;
  q = __fadd_rn(__fmul_rn(x2, q), 1.18534705686654e-04f);
  q = __fadd_rn(__fmul_rn(x2, q), 2.26843463243900e-03f);
  q = __fadd_rn(__fmul_rn(x2, q), 4.89352518554385e-03f);
  float r = __fdiv_rn(p, q);
  return (fabsf(x) < 0.0004f) ? x : r;
}

__device__ __forceinline__ float xla_sigmoidf(float x) {
  return __fadd_rn(0.5f, __fmul_rn(0.5f, xla_tanhf(__fmul_rn(0.5f, x))));
}

__device__ __forceinline__ uint32_t rotl32(uint32_t v, int r) {
  return (v << r) | (v >> (32 - r));
}
__device__ __forceinline__ void threefry2x32(uint32_t k0, uint32_t k1,
                                             uint32_t x0, uint32_t x1,
                                             uint32_t& o0, uint32_t& o1) {
  uint32_t k2 = k0 ^ k1 ^ 0x1BD11BDAu;
  x0 += k0; x1 += k1;
  #define TFR(r) { x0 += x1; x1 = rotl32(x1, r); x1 ^= x0; }
  TFR(13) TFR(15) TFR(26) TFR(6)
  x0 += k1; x1 += k2 + 1u;
  TFR(17) TFR(29) TFR(16) TFR(24)
  x0 += k2; x1 += k0 + 2u;
  TFR(13) TFR(15) TFR(26) TFR(6)
  x0 += k0; x1 += k1 + 3u;
  TFR(17) TFR(29) TFR(16) TFR(24)
  x0 += k1; x1 += k2 + 4u;
  TFR(13) TFR(15) TFR(26) TFR(6)
  x0 += k2; x1 += k0 + 5u;
  #undef TFR
  o0 = x0; o1 = x1;
}

__device__ __forceinline__ float bits_to_gumbel(uint32_t bits) {
  const float kTiny = 1.1754943508222875e-38f;
  float f = __fsub_rn(__uint_as_float((bits >> 9) | 0x3F800000u), 1.0f);
  float u = __fadd_rn(__fmul_rn(f, __fsub_rn(1.0f, kTiny)), kTiny);
  u = fmaxf(kTiny, u);
  return -logf(-logf(u));
}

// ---------------- persistent kernel: 512 threads, 2 rows/block ----------------
// waves 0-3 (t<256): row A = blockIdx.x ; waves 4-7 (t>=256): row B = blockIdx.x+256
__global__ __launch_bounds__(512, 2) void k_decode(
    const float* __restrict__ stat, const float* __restrict__ dyn,
    const float* __restrict__ sW,   const float* __restrict__ sb,
    const float* __restrict__ dW,   const float* __restrict__ db,
    const float* __restrict__ x0,   const float* __restrict__ h0,
    const float* __restrict__ Wemb, const float* __restrict__ bemb,
    const float* __restrict__ Wih,  const float* __restrict__ Whh,
    const float* __restrict__ bih,  const float* __restrict__ bhh,
    const float* __restrict__ Wa,   const float* __restrict__ va,
    const float* __restrict__ Wd,   const float* __restrict__ vd,
    float* __restrict__ out) {

  __shared__ __align__(16) float stA0[NS], stA1[NS], dyA0[NS], dyA1[NS];
  __shared__ __align__(16) float stB0[NS], stB1[NS], dyB0[NS], dyB1[NS];
  __shared__ float4 AF4[NH];               // {As0,As1,Ad0,Ad1}
  __shared__ float2 AF2[NH];               // {Ac, va}
  __shared__ float4 DF4[NH];               // {Ds0,Ds1,Dc,vd}
  __shared__ float4 CW4[NH];               // {Cw0,Cw1,Cwb,0}
  __shared__ float WembL[2*NH], bembL[NH];
  __shared__ float bihL[NH3], bhhL[NH3];
  __shared__ __align__(16) float embA[NH], embB[NH], hA[NH], hB[NH];
  __shared__ float giA[NH3], ghA[NH3], giB[NH3], ghB[NH3];
  __shared__ float HtA[NH], HtB[NH];       // Hterm, reused as Cterm
  __shared__ float ex2A[NS], ex2B[NS];
  __shared__ uint32_t keysL[2*NS];
  __shared__ float xpA[2], xpB[2];
  __shared__ float part[8][8];
  __shared__ int   partI[8][2];

  const int t = threadIdx.x;
  const int w = t >> 6;                    // wave 0..7
  const int bA = blockIdx.x;
  const int bB = blockIdx.x + NBLK;
  const bool grpA = (t < 256);
  const int s = grpA ? t : (t - 256);      // candidate node index for S-loops
  const bool activeS = (s < NS);

  // ---- one-time setup ----
  if (t < NS) {
    stA0[t] = stat[(size_t)bA*2*NS + t];
    stA1[t] = stat[(size_t)bA*2*NS + NS + t];
    dyA0[t] = dyn[(size_t)bA*2*NS + t];
    dyA1[t] = dyn[(size_t)bA*2*NS + NS + t];
    uint32_t q0, q1;
    threefry2x32(0u, 42u, 0u, (uint32_t)t, q0, q1);
    keysL[2*t] = q0; keysL[2*t + 1] = q1;
  } else if (t >= 256 && t < 256 + NS) {
    stB0[s] = stat[(size_t)bB*2*NS + s];
    stB1[s] = stat[(size_t)bB*2*NS + NS + s];
    dyB0[s] = dyn[(size_t)bB*2*NS + s];
    dyB1[s] = dyn[(size_t)bB*2*NS + NS + s];
  }
  // folded attention/decoder vectors (identical math to rounds 2-4)
  if (t < NH) {
    int h = t;
    const float* war = Wa + (size_t)h * NH3;
    float as0 = 0.f, as1 = 0.f, ad0 = 0.f, ad1 = 0.f, ac = 0.f;
    for (int k = 0; k < NH; ++k) {
      as0 = fmaf(war[k],     sW[k*2+0], as0);
      as1 = fmaf(war[k],     sW[k*2+1], as1);
      ad0 = fmaf(war[NH+k],  dW[k*2+0], ad0);
      ad1 = fmaf(war[NH+k],  dW[k*2+1], ad1);
      ac  = fmaf(war[k],     sb[k],     ac);
    }
    for (int k = 0; k < NH; ++k) ac = fmaf(war[NH+k], db[k], ac);
    AF4[h] = make_float4(as0, as1, ad0, ad1);
    AF2[h] = make_float2(ac, va[h]);

    const float* wdr = Wd + (size_t)h * 256;
    float ds0 = 0.f, ds1 = 0.f, dc = 0.f, c0 = 0.f, c1 = 0.f, cb = 0.f;
    for (int k = 0; k < NH; ++k) {
      ds0 = fmaf(wdr[k],    sW[k*2+0], ds0);
      ds1 = fmaf(wdr[k],    sW[k*2+1], ds1);
      dc  = fmaf(wdr[k],    sb[k],     dc);
      c0  = fmaf(wdr[NH+k], sW[k*2+0], c0);
      c1  = fmaf(wdr[NH+k], sW[k*2+1], c1);
      cb  = fmaf(wdr[NH+k], sb[k],     cb);
    }
    DF4[h] = make_float4(ds0, ds1, dc, vd[h]);
    CW4[h] = make_float4(c0, c1, cb, 0.f);

    bembL[h] = bemb[h];
    WembL[2*h]   = Wemb[2*h];
    WembL[2*h+1] = Wemb[2*h+1];
    hA[h] = h0[h];
    hB[h] = h0[h];
  }
  for (int i = t; i < NH3; i += 512) { bihL[i] = bih[i]; bhhL[i] = bhh[i]; }
  if (t == 0)   { xpA[0] = x0[0]; xpA[1] = x0[1]; }
  if (t == 256) { xpB[0] = x0[0]; xpB[1] = x0[1]; }
  __syncthreads();

  // GRU dot assignment: bl = row, jl = dot lane (0..255); dots jl, jl+256, jl+512
  const int bl = t & 1;
  const int jl = t >> 1;
  const float4* p0 = (const float4*)(Wih + (size_t)jl * NH);
  const float4* p1 = (jl < NH)
      ? (const float4*)(Wih + (size_t)(256 + jl) * NH)
      : (const float4*)(Whh + (size_t)(jl - NH) * NH);
  const float4* p2 = (const float4*)(Whh + (size_t)(jl + NH) * NH);
  const float4* e4 = (const float4*)(bl ? embB : embA);
  const float4* h4 = (const float4*)(bl ? hB : hA);
  float* gi = bl ? giB : giA;
  float* gh = bl ? ghB : ghA;

  // ---- 200 decode steps ----
  for (int step = 0; step < NS; ++step) {
    // S0: emb = x @ Wemb^T + bemb
    if (t < NH) {
      float e = fmaf(xpA[1], WembL[t*2+1], __fmul_rn(xpA[0], WembL[t*2+0]));
      embA[t] = __fadd_rn(e, bembL[t]);
    } else if (t >= 256 && t < 256 + NH) {
      int h = t - 256;
      float e = fmaf(xpB[1], WembL[h*2+1], __fmul_rn(xpB[0], WembL[h*2+0]));
      embB[h] = __fadd_rn(e, bembL[h]);
    }
    __syncthreads();

    // S1: GRU dots, weights streamed from L2 (exact sequential-k per dot)
    {
      float a0 = 0.f, a1 = 0.f, a2 = 0.f;
      #define GRU_DOT(SVSEL)                                             \
        _Pragma("unroll 8")                                              \
        for (int k4 = 0; k4 < 32; ++k4) {                                \
          float4 c0 = p0[k4], c1 = p1[k4], c2 = p2[k4];                  \
          float4 ev = e4[k4], hv = h4[k4];                               \
          float4 sv = SVSEL;                                             \
          a0 = fmaf(c0.x, ev.x, a0); a0 = fmaf(c0.y, ev.y, a0);          \
          a0 = fmaf(c0.z, ev.z, a0); a0 = fmaf(c0.w, ev.w, a0);          \
          a1 = fmaf(c1.x, sv.x, a1); a1 = fmaf(c1.y, sv.y, a1);          \
          a1 = fmaf(c1.z, sv.z, a1); a1 = fmaf(c1.w, sv.w, a1);          \
          a2 = fmaf(c2.x, hv.x, a2); a2 = fmaf(c2.y, hv.y, a2);          \
          a2 = fmaf(c2.z, hv.z, a2); a2 = fmaf(c2.w, hv.w, a2);          \
        }
      if (jl < NH) { GRU_DOT(ev) } else { GRU_DOT(hv) }
      #undef GRU_DOT
      gi[jl] = __fadd_rn(a0, bihL[jl]);
      if (jl < NH) gi[256 + jl] = __fadd_rn(a1, bihL[256 + jl]);
      else         gh[jl - NH]  = __fadd_rn(a1, bhhL[jl - NH]);
      gh[jl + NH] = __fadd_rn(a2, bhhL[jl + NH]);
    }
    __syncthreads();

    // S2: gates (torch r,z,n), h_new in place
    if (t < NH) {
      float r = xla_sigmoidf(__fadd_rn(giA[t],      ghA[t]));
      float z = xla_sigmoidf(__fadd_rn(giA[t+NH],   ghA[t+NH]));
      float n = xla_tanhf(__fadd_rn(giA[t+2*NH], __fmul_rn(r, ghA[t+2*NH])));
      float hv = hA[t];
      hA[t] = __fadd_rn(__fmul_rn(__fsub_rn(1.0f, z), n), __fmul_rn(z, hv));
    } else if (t >= 256 && t < 256 + NH) {
      int h = t - 256;
      float r = xla_sigmoidf(__fadd_rn(giB[h],      ghB[h]));
      float z = xla_sigmoidf(__fadd_rn(giB[h+NH],   ghB[h+NH]));
      float n = xla_tanhf(__fadd_rn(giB[h+2*NH], __fmul_rn(r, ghB[h+2*NH])));
      float hv = hB[h];
      hB[h] = __fadd_rn(__fmul_rn(__fsub_rn(1.0f, z), n), __fmul_rn(z, hv));
    }
    __syncthreads();

    // S3: Hterm = Wa[:,256:384] @ h_new (exact round-2 float4 order)
    if (t < NH) {
      const float4* war = (const float4*)(Wa + (size_t)t*NH3 + 2*NH);
      const float4* hn4 = (const float4*)hA;
      float acc = 0.f;
      #pragma unroll 8
      for (int k4 = 0; k4 < 32; ++k4) {
        float4 a = war[k4], hv = hn4[k4];
        acc = fmaf(a.x, hv.x, acc); acc = fmaf(a.y, hv.y, acc);
        acc = fmaf(a.z, hv.z, acc); acc = fmaf(a.w, hv.w, acc);
      }
      HtA[t] = acc;
    } else if (t >= NH && t < 256) {
      int h = t - NH;
      const float4* war = (const float4*)(Wa + (size_t)h*NH3 + 2*NH);
      const float4* hn4 = (const float4*)hB;
      float acc = 0.f;
      #pragma unroll 8
      for (int k4 = 0; k4 < 32; ++k4) {
        float4 a = war[k4], hv = hn4[k4];
        acc = fmaf(a.x, hv.x, acc); acc = fmaf(a.y, hv.y, acc);
        acc = fmaf(a.z, hv.z, acc); acc = fmaf(a.w, hv.w, acc);
      }
      HtB[h] = acc;
    }
    __syncthreads();

    // S4: attention scores (row by wave group)
    float s0 = 0.f, s1 = 0.f, d0 = 0.f, d1 = 0.f;
    const float* Htp = grpA ? HtA : HtB;
    if (activeS) {
      if (grpA) { s0 = stA0[s]; s1 = stA1[s]; d0 = dyA0[s]; d1 = dyA1[s]; }
      else      { s0 = stB0[s]; s1 = stB1[s]; d0 = dyB0[s]; d1 = dyB1[s]; }
    }
    float sc = -INFINITY;
    if (activeS) {
      float acc = 0.f;
      #pragma unroll 2
      for (int h = 0; h < NH; ++h) {
        float4 af = AF4[h]; float2 a2 = AF2[h]; float ht = Htp[h];
        float e = fmaf(af.y, s1, __fmul_rn(af.x, s0));
        e = fmaf(af.z, d0, e);
        e = fmaf(af.w, d1, e);
        e = __fadd_rn(e, a2.x);
        e = __fadd_rn(e, ht);
        acc = fmaf(a2.y, xla_tanhf(e), acc);
      }
      sc = acc;
    }

    // attn max (order-independent)
    {
      float m = sc;
      #pragma unroll
      for (int mm = 1; mm < 64; mm <<= 1) m = fmaxf(m, __shfl_xor(m, mm));
      if ((t & 63) == 0) part[w][0] = m;
    }
    __syncthreads();
    const int wb = grpA ? 0 : 4;
    float mx = fmaxf(fmaxf(part[wb][0], part[wb+1][0]),
                     fmaxf(part[wb+2][0], part[wb+3][0]));

    // exp + sum + context partials
    float exv = 0.f;
    if (activeS) exv = expf(__fsub_rn(sc, mx));
    {
      float sm = exv;
      float c0 = activeS ? __fmul_rn(exv, s0) : 0.f;
      float c1 = activeS ? __fmul_rn(exv, s1) : 0.f;
      #pragma unroll
      for (int mm = 1; mm < 64; mm <<= 1) {
        sm = __fadd_rn(sm, __shfl_xor(sm, mm));
        c0 = __fadd_rn(c0, __shfl_xor(c0, mm));
        c1 = __fadd_rn(c1, __shfl_xor(c1, mm));
      }
      if ((t & 63) == 0) { part[w][1] = sm; part[w][2] = c0; part[w][3] = c1; }
    }
    __syncthreads();

    // Cterm (reuse HtA/HtB): Ct = (R0/sume)*Cw0 + (R1/sume)*Cw1 + Cwb
    if (t < 256) {
      int h = t & 127;
      int g = (t < NH) ? 0 : 4;
      float sume = __fadd_rn(__fadd_rn(__fadd_rn(part[g][1], part[g+1][1]), part[g+2][1]), part[g+3][1]);
      float r0   = __fadd_rn(__fadd_rn(__fadd_rn(part[g][2], part[g+1][2]), part[g+2][2]), part[g+3][2]);
      float r1   = __fadd_rn(__fadd_rn(__fadd_rn(part[g][3], part[g+1][3]), part[g+2][3]), part[g+3][3]);
      r0 = __fdiv_rn(r0, sume); r1 = __fdiv_rn(r1, sume);
      float4 cw = CW4[h];
      float ct = fmaf(r0, cw.x, fmaf(r1, cw.y, cw.z));
      if (t < NH) HtA[h] = ct; else HtB[h] = ct;
    }
    __syncthreads();

    // S5: decoder logits
    float sc2 = -INFINITY;
    if (activeS) {
      float acc = 0.f;
      #pragma unroll 2
      for (int h = 0; h < NH; ++h) {
        float4 df = DF4[h]; float ct = Htp[h];
        float d = fmaf(df.y, s1, __fmul_rn(df.x, s0));
        d = __fadd_rn(d, df.z);
        d = __fadd_rn(d, ct);
        acc = fmaf(df.w, xla_tanhf(d), acc);
      }
      sc2 = acc;
    }

    // decoder max
    {
      float m = sc2;
      #pragma unroll
      for (int mm = 1; mm < 64; mm <<= 1) m = fmaxf(m, __shfl_xor(m, mm));
      if ((t & 63) == 0) part[w][4] = m;
    }
    __syncthreads();
    float m2 = fmaxf(fmaxf(part[wb][4], part[wb+1][4]),
                     fmaxf(part[wb+2][4], part[wb+3][4]));

    // decoder exp + sum (store ex for winner prob)
    float e2 = 0.f;
    if (activeS) {
      e2 = expf(__fsub_rn(sc2, m2));
      if (grpA) ex2A[s] = e2; else ex2B[s] = e2;
    }
    {
      float sm = e2;
      #pragma unroll
      for (int mm = 1; mm < 64; mm <<= 1) sm = __fadd_rn(sm, __shfl_xor(sm, mm));
      if ((t & 63) == 0) part[w][5] = sm;
    }

    // gumbel-max sampling (bit-exact threefry, first-index tiebreak)
    uint32_t k0 = keysL[2*step], k1 = keysL[2*step + 1];
    float gv = -INFINITY;
    int gidx = NS;
    if (activeS) {
      int brow = grpA ? bA : bB;
      uint32_t q0, q1;
      threefry2x32(k0, k1, 0u, (uint32_t)(brow*NS + s), q0, q1);
      gv = __fadd_rn(bits_to_gumbel(q0 ^ q1), sc2);
      gidx = s;
    }
    #pragma unroll
    for (int mm = 1; mm < 64; mm <<= 1) {
      float ov = __shfl_xor(gv, mm); int oi = __shfl_xor(gidx, mm);
      if (ov > gv || (ov == gv && oi < gidx)) { gv = ov; gidx = oi; }
    }
    if ((t & 63) == 0) { part[w][6] = gv; partI[w][0] = gidx; }
    __syncthreads();

    if (t == 0) {
      float bv = part[0][6]; int bi = partI[0][0];
      #pragma unroll
      for (int ww = 1; ww < 4; ++ww) {
        float v2 = part[ww][6]; int i2 = partI[ww][0];
        if (v2 > bv || (v2 == bv && i2 < bi)) { bv = v2; bi = i2; }
      }
      float sume2 = __fadd_rn(__fadd_rn(__fadd_rn(part[0][5], part[1][5]), part[2][5]), part[3][5]);
      out[(size_t)bA*NS + step] = (float)bi;
      out[(size_t)NB*NS + (size_t)bA*NS + step] = __fdiv_rn(ex2A[bi], sume2);
      xpA[0] = stA0[bi]; xpA[1] = stA1[bi];
    } else if (t == 256) {
      float bv = part[4][6]; int bi = partI[4][0];
      #pragma unroll
      for (int ww = 5; ww < 8; ++ww) {
        float v2 = part[ww][6]; int i2 = partI[ww][0];
        if (v2 > bv || (v2 == bv && i2 < bi)) { bv = v2; bi = i2; }
      }
      float sume2 = __fadd_rn(__fadd_rn(__fadd_rn(part[4][5], part[5][5]), part[6][5]), part[7][5]);
      out[(size_t)bB*NS + step] = (float)bi;
      out[(size_t)NB*NS + (size_t)bB*NS + step] = __fdiv_rn(ex2B[bi], sume2);
      xpB[0] = stB0[bi]; xpB[1] = stB1[bi];
    }
    __syncthreads();
  }
}

// ---------------- host launch ----------------
extern "C" void kernel_launch(void* const* d_in, const int* in_sizes, int n_in,
                              void* d_out, int out_size, void* d_ws, size_t ws_size,
                              hipStream_t stream) {
  (void)in_sizes; (void)n_in; (void)out_size; (void)d_ws; (void)ws_size;
  const float* stat = (const float*)d_in[0];
  const float* dyn  = (const float*)d_in[1];
  const float* sW   = (const float*)d_in[2];
  const float* sb   = (const float*)d_in[3];
  const float* dW   = (const float*)d_in[4];
  const float* db   = (const float*)d_in[5];
  const float* x0   = (const float*)d_in[6];
  const float* h0   = (const float*)d_in[7];
  const float* Wemb = (const float*)d_in[8];
  const float* bemb = (const float*)d_in[9];
  const float* Wih  = (const float*)d_in[10];
  const float* Whh  = (const float*)d_in[11];
  const float* bih  = (const float*)d_in[12];
  const float* bhh  = (const float*)d_in[13];
  const float* Wa   = (const float*)d_in[14];
  const float* va   = (const float*)d_in[15];
  const float* Wd   = (const float*)d_in[16];
  const float* vd   = (const float*)d_in[17];
  float* out = (float*)d_out;

  k_decode<<<NBLK, 512, 0, stream>>>(stat, dyn, sW, sb, dW, db, x0, h0,
                                     Wemb, bemb, Wih, Whh, bih, bhh,
                                     Wa, va, Wd, vd, out);
}

// Round 6
// 7873.720 us; speedup vs baseline: 2.5241x; 1.1256x over previous
//
#include <hip/hip_runtime.h>
#include <stdint.h>
#include <math.h>

#define NB 512
#define NS 200
#define NH 128
#define NH3 384

// ---------------- XLA-exact scalar helpers ----------------
__device__ __forceinline__ float xla_tanhf(float x) {
  float cx = fminf(fmaxf(x, -9.0f), 9.0f);
  float x2 = __fmul_rn(cx, cx);
  float p = -2.76076847742355e-16f;
  p = __fadd_rn(__fmul_rn(x2, p), 2.00018790482477e-13f);
  p = __fadd_rn(__fmul_rn(x2, p), -8.60467152213735e-11f);
  p = __fadd_rn(__fmul_rn(x2, p), 5.12229709037114e-08f);
  p = __fadd_rn(__fmul_rn(x2, p), 1.48572235717979e-05f);
  p = __fadd_rn(__fmul_rn(x2, p), 6.37261928875436e-04f);
  p = __fadd_rn(__fmul_rn(x2, p), 4.89352455891786e-03f);
  p = __fmul_rn(cx, p);
  float q = 1.19825839466702e-06f;
  q = __fadd_rn(__fmul_rn(x2, q), 1.18534705686654e-04f);
  q = __fadd_rn(__fmul_rn(x2, q), 2.26843463243900e-03f);
  q = __fadd_rn(__fmul_rn(x2, q), 4.89352518554385e-03f);
  float r = __fdiv_rn(p, q);
  return (fabsf(x) < 0.0004f) ? x : r;
}

__device__ __forceinline__ float xla_sigmoidf(float x) {
  return __fadd_rn(0.5f, __fmul_rn(0.5f, xla_tanhf(__fmul_rn(0.5f, x))));
}

__device__ __forceinline__ uint32_t rotl32(uint32_t v, int r) {
  return (v << r) | (v >> (32 - r));
}
__device__ __forceinline__ void threefry2x32(uint32_t k0, uint32_t k1,
                                             uint32_t x0, uint32_t x1,
                                             uint32_t& o0, uint32_t& o1) {
  uint32_t k2 = k0 ^ k1 ^ 0x1BD11BDAu;
  x0 += k0; x1 += k1;
  #define TFR(r) { x0 += x1; x1 = rotl32(x1, r); x1 ^= x0; }
  TFR(13) TFR(15) TFR(26) TFR(6)
  x0 += k1; x1 += k2 + 1u;
  TFR(17) TFR(29) TFR(16) TFR(24)
  x0 += k2; x1 += k0 + 2u;
  TFR(13) TFR(15) TFR(26) TFR(6)
  x0 += k0; x1 += k1 + 3u;
  TFR(17) TFR(29) TFR(16) TFR(24)
  x0 += k1; x1 += k2 + 4u;
  TFR(13) TFR(15) TFR(26) TFR(6)
  x0 += k2; x1 += k0 + 5u;
  #undef TFR
  o0 = x0; o1 = x1;
}

__device__ __forceinline__ float bits_to_gumbel(uint32_t bits) {
  const float kTiny = 1.1754943508222875e-38f;
  float f = __fsub_rn(__uint_as_float((bits >> 9) | 0x3F800000u), 1.0f);
  float u = __fadd_rn(__fmul_rn(f, __fsub_rn(1.0f, kTiny)), kTiny);
  u = fmaxf(kTiny, u);
  return -logf(-logf(u));
}

// ---------------- persistent kernel: 1 row/block, 512 threads, h-split ----
// group 0 (t<256): s-lane t, h in [0,64) for S4/S5 partials + all reductions
// group 1 (t>=256): s-lane t-256, h in [64,128) partials
__global__ __launch_bounds__(512, 4) void k_decode(
    const float* __restrict__ stat, const float* __restrict__ dyn,
    const float* __restrict__ sW,   const float* __restrict__ sb,
    const float* __restrict__ dW,   const float* __restrict__ db,
    const float* __restrict__ x0,   const float* __restrict__ h0,
    const float* __restrict__ Wemb, const float* __restrict__ bemb,
    const float* __restrict__ Wih,  const float* __restrict__ Whh,
    const float* __restrict__ bih,  const float* __restrict__ bhh,
    const float* __restrict__ Wa,   const float* __restrict__ va,
    const float* __restrict__ Wd,   const float* __restrict__ vd,
    float* __restrict__ out) {

  __shared__ __align__(16) float st0L[NS], st1L[NS], dy0L[NS], dy1L[NS];
  __shared__ float4 AF4[NH];               // {As0,As1,Ad0,Ad1}
  __shared__ float2 AF2[NH];               // {Ac, va}
  __shared__ float4 DF4[NH];               // {Ds0,Ds1,Dc,vd}
  __shared__ float4 CW4[NH];               // {Cw0,Cw1,Cwb,0}
  __shared__ float WembL[2*NH], bembL[NH];
  __shared__ float bihL[NH3], bhhL[NH3];
  __shared__ __align__(16) float embL[NH], hL[NH];
  __shared__ float giL[NH3], ghL[NH3];
  __shared__ float HtL[NH];                // Hterm, overwritten by Cterm
  __shared__ float scP[256];               // group-1 h-half partials
  __shared__ float ex2L[NS];
  __shared__ uint32_t keysL[2*NS];
  __shared__ float xpL[2];
  __shared__ float part[4][8];
  __shared__ int   partI[4];

  const int t = threadIdx.x;
  const int b = blockIdx.x;
  const int w = t >> 6;                    // wave 0..7
  const int g = t >> 8;                    // h-half group 0/1
  const int s = t & 255;                   // candidate node index
  const bool activeS = (s < NS);
  const int h0i = g * 64;

  // ---- one-time setup ----
  if (t < NS) {
    st0L[t] = stat[(size_t)b*2*NS + t];
    st1L[t] = stat[(size_t)b*2*NS + NS + t];
    dy0L[t] = dyn[(size_t)b*2*NS + t];
    dy1L[t] = dyn[(size_t)b*2*NS + NS + t];
    uint32_t q0, q1;
    threefry2x32(0u, 42u, 0u, (uint32_t)t, q0, q1);
    keysL[2*t] = q0; keysL[2*t + 1] = q1;
  }
  // folded attention/decoder vectors (identical math to rounds 2-5)
  if (t < NH) {
    int h = t;
    const float* war = Wa + (size_t)h * NH3;
    float as0 = 0.f, as1 = 0.f, ad0 = 0.f, ad1 = 0.f, ac = 0.f;
    for (int k = 0; k < NH; ++k) {
      as0 = fmaf(war[k],     sW[k*2+0], as0);
      as1 = fmaf(war[k],     sW[k*2+1], as1);
      ad0 = fmaf(war[NH+k],  dW[k*2+0], ad0);
      ad1 = fmaf(war[NH+k],  dW[k*2+1], ad1);
      ac  = fmaf(war[k],     sb[k],     ac);
    }
    for (int k = 0; k < NH; ++k) ac = fmaf(war[NH+k], db[k], ac);
    AF4[h] = make_float4(as0, as1, ad0, ad1);
    AF2[h] = make_float2(ac, va[h]);

    const float* wdr = Wd + (size_t)h * 256;
    float ds0 = 0.f, ds1 = 0.f, dc = 0.f, c0 = 0.f, c1 = 0.f, cb = 0.f;
    for (int k = 0; k < NH; ++k) {
      ds0 = fmaf(wdr[k],    sW[k*2+0], ds0);
      ds1 = fmaf(wdr[k],    sW[k*2+1], ds1);
      dc  = fmaf(wdr[k],    sb[k],     dc);
      c0  = fmaf(wdr[NH+k], sW[k*2+0], c0);
      c1  = fmaf(wdr[NH+k], sW[k*2+1], c1);
      cb  = fmaf(wdr[NH+k], sb[k],     cb);
    }
    DF4[h] = make_float4(ds0, ds1, dc, vd[h]);
    CW4[h] = make_float4(c0, c1, cb, 0.f);

    bembL[h] = bemb[h];
    WembL[2*h]   = Wemb[2*h];
    WembL[2*h+1] = Wemb[2*h+1];
    hL[h] = h0[h];
  }
  for (int i = t; i < NH3; i += 512) { bihL[i] = bih[i]; bhhL[i] = bhh[i]; }
  if (t == 0) { xpL[0] = x0[0]; xpL[1] = x0[1]; }
  __syncthreads();

  // hoist per-s inputs into registers (constant across steps)
  float s0r = 0.f, s1r = 0.f, d0r = 0.f, d1r = 0.f;
  if (activeS) {
    s0r = st0L[s]; s1r = st1L[s]; d0r = dy0L[s]; d1r = dy1L[s];
  }

  // ---- 200 decode steps ----
  for (int step = 0; step < NS; ++step) {
    // S0: emb = x @ Wemb^T + bemb  (t<128)
    if (t < NH) {
      float e = fmaf(xpL[1], WembL[t*2+1], __fmul_rn(xpL[0], WembL[t*2+0]));
      embL[t] = __fadd_rn(e, bembL[t]);
    }
    __syncthreads();

    // S1: 768 GRU dots over 512 threads (per-dot chain identical to r5)
    if (t < 256) {
      // fused: dot t (Wih row t · emb) and dot 512+t (Whh row 128+t · h)
      const float4* wp0 = (const float4*)(Wih + (size_t)t * NH);
      const float4* wp1 = (const float4*)(Whh + (size_t)(NH + t) * NH);
      const float4* e4 = (const float4*)embL;
      const float4* h4 = (const float4*)hL;
      float a0 = 0.f, a1 = 0.f;
      #pragma unroll 8
      for (int k4 = 0; k4 < 32; ++k4) {
        float4 c0 = wp0[k4], c1 = wp1[k4];
        float4 ev = e4[k4],  hv = h4[k4];
        a0 = fmaf(c0.x, ev.x, a0); a0 = fmaf(c0.y, ev.y, a0);
        a0 = fmaf(c0.z, ev.z, a0); a0 = fmaf(c0.w, ev.w, a0);
        a1 = fmaf(c1.x, hv.x, a1); a1 = fmaf(c1.y, hv.y, a1);
        a1 = fmaf(c1.z, hv.z, a1); a1 = fmaf(c1.w, hv.w, a1);
      }
      giL[t]      = __fadd_rn(a0, bihL[t]);
      ghL[NH + t] = __fadd_rn(a1, bhhL[NH + t]);
    } else {
      const bool isWih = (t < NH3);
      const float4* wp = isWih
          ? (const float4*)(Wih + (size_t)t * NH)
          : (const float4*)(Whh + (size_t)(t - NH3) * NH);
      const float4* op = isWih ? (const float4*)embL : (const float4*)hL;
      float a0 = 0.f;
      #pragma unroll 8
      for (int k4 = 0; k4 < 32; ++k4) {
        float4 c = wp[k4], v = op[k4];
        a0 = fmaf(c.x, v.x, a0); a0 = fmaf(c.y, v.y, a0);
        a0 = fmaf(c.z, v.z, a0); a0 = fmaf(c.w, v.w, a0);
      }
      if (isWih) giL[t]       = __fadd_rn(a0, bihL[t]);
      else       ghL[t - NH3] = __fadd_rn(a0, bhhL[t - NH3]);
    }
    __syncthreads();

    // S2: gates (torch r,z,n), h_new in place (t<128)
    if (t < NH) {
      float r = xla_sigmoidf(__fadd_rn(giL[t],      ghL[t]));
      float z = xla_sigmoidf(__fadd_rn(giL[t+NH],   ghL[t+NH]));
      float n = xla_tanhf(__fadd_rn(giL[t+2*NH], __fmul_rn(r, ghL[t+2*NH])));
      float hv = hL[t];
      hL[t] = __fadd_rn(__fmul_rn(__fsub_rn(1.0f, z), n), __fmul_rn(z, hv));
    }
    __syncthreads();

    // S3: Hterm = Wa[:,256:384] @ h_new (exact r2 float4 chain, t<128)
    if (t < NH) {
      const float4* war = (const float4*)(Wa + (size_t)t*NH3 + 2*NH);
      const float4* hn4 = (const float4*)hL;
      float acc = 0.f;
      #pragma unroll 8
      for (int k4 = 0; k4 < 32; ++k4) {
        float4 a = war[k4], hv = hn4[k4];
        acc = fmaf(a.x, hv.x, acc); acc = fmaf(a.y, hv.y, acc);
        acc = fmaf(a.z, hv.z, acc); acc = fmaf(a.w, hv.w, acc);
      }
      HtL[t] = acc;
    }
    __syncthreads();

    // S4: attention scores, h-halves split across groups
    float accA = 0.f;
    if (activeS) {
      #pragma unroll 2
      for (int h = h0i; h < h0i + 64; ++h) {
        float4 af = AF4[h]; float2 a2 = AF2[h]; float ht = HtL[h];
        float e = fmaf(af.y, s1r, __fmul_rn(af.x, s0r));
        e = fmaf(af.z, d0r, e);
        e = fmaf(af.w, d1r, e);
        e = __fadd_rn(e, a2.x);
        e = __fadd_rn(e, ht);
        accA = fmaf(a2.y, xla_tanhf(e), accA);
      }
    }
    if (g == 1 && activeS) scP[s] = accA;
    __syncthreads();
    float sc = -INFINITY;
    if (g == 0 && activeS) sc = __fadd_rn(accA, scP[s]);

    // attn max (group 0)
    if (g == 0) {
      float m = sc;
      #pragma unroll
      for (int mm = 1; mm < 64; mm <<= 1) m = fmaxf(m, __shfl_xor(m, mm));
      if ((t & 63) == 0) part[w][0] = m;
    }
    __syncthreads();
    float mx = fmaxf(fmaxf(part[0][0], part[1][0]), fmaxf(part[2][0], part[3][0]));

    // exp + sum + context partials (group 0)
    float exv = 0.f;
    if (g == 0 && activeS) exv = expf(__fsub_rn(sc, mx));
    if (g == 0) {
      float sm = exv;
      float c0 = activeS ? __fmul_rn(exv, s0r) : 0.f;
      float c1 = activeS ? __fmul_rn(exv, s1r) : 0.f;
      #pragma unroll
      for (int mm = 1; mm < 64; mm <<= 1) {
        sm = __fadd_rn(sm, __shfl_xor(sm, mm));
        c0 = __fadd_rn(c0, __shfl_xor(c0, mm));
        c1 = __fadd_rn(c1, __shfl_xor(c1, mm));
      }
      if ((t & 63) == 0) { part[w][1] = sm; part[w][2] = c0; part[w][3] = c1; }
    }
    __syncthreads();

    // Cterm (overwrite HtL): Ct = (R0/sume)*Cw0 + (R1/sume)*Cw1 + Cwb
    if (t < NH) {
      float sume = __fadd_rn(__fadd_rn(__fadd_rn(part[0][1], part[1][1]), part[2][1]), part[3][1]);
      float r0   = __fadd_rn(__fadd_rn(__fadd_rn(part[0][2], part[1][2]), part[2][2]), part[3][2]);
      float r1   = __fadd_rn(__fadd_rn(__fadd_rn(part[0][3], part[1][3]), part[2][3]), part[3][3]);
      r0 = __fdiv_rn(r0, sume); r1 = __fdiv_rn(r1, sume);
      float4 cw = CW4[t];
      HtL[t] = fmaf(r0, cw.x, fmaf(r1, cw.y, cw.z));
    }
    __syncthreads();

    // S5: decoder logits, h-halves split
    float accD = 0.f;
    if (activeS) {
      #pragma unroll 2
      for (int h = h0i; h < h0i + 64; ++h) {
        float4 df = DF4[h]; float ct = HtL[h];
        float d = fmaf(df.y, s1r, __fmul_rn(df.x, s0r));
        d = __fadd_rn(d, df.z);
        d = __fadd_rn(d, ct);
        accD = fmaf(df.w, xla_tanhf(d), accD);
      }
    }
    if (g == 1 && activeS) scP[s] = accD;
    __syncthreads();
    float sc2 = -INFINITY;
    if (g == 0 && activeS) sc2 = __fadd_rn(accD, scP[s]);

    // decoder max (group 0)
    if (g == 0) {
      float m = sc2;
      #pragma unroll
      for (int mm = 1; mm < 64; mm <<= 1) m = fmaxf(m, __shfl_xor(m, mm));
      if ((t & 63) == 0) part[w][4] = m;
    }
    __syncthreads();
    float m2 = fmaxf(fmaxf(part[0][4], part[1][4]), fmaxf(part[2][4], part[3][4]));

    // decoder exp/sum + gumbel argmax (group 0)
    if (g == 0) {
      float e2 = 0.f;
      if (activeS) {
        e2 = expf(__fsub_rn(sc2, m2));
        ex2L[s] = e2;
      }
      float sm = e2;
      #pragma unroll
      for (int mm = 1; mm < 64; mm <<= 1) sm = __fadd_rn(sm, __shfl_xor(sm, mm));
      if ((t & 63) == 0) part[w][5] = sm;

      uint32_t k0 = keysL[2*step], k1 = keysL[2*step + 1];
      float gv = -INFINITY;
      int gidx = 256;
      if (activeS) {
        uint32_t q0, q1;
        threefry2x32(k0, k1, 0u, (uint32_t)(b*NS + s), q0, q1);
        gv = __fadd_rn(bits_to_gumbel(q0 ^ q1), sc2);
        gidx = s;
      }
      #pragma unroll
      for (int mm = 1; mm < 64; mm <<= 1) {
        float ov = __shfl_xor(gv, mm); int oi = __shfl_xor(gidx, mm);
        if (ov > gv || (ov == gv && oi < gidx)) { gv = ov; gidx = oi; }
      }
      if ((t & 63) == 0) { part[w][6] = gv; partI[w] = gidx; }
    }
    __syncthreads();

    if (t == 0) {
      float bv = part[0][6]; int bi = partI[0];
      #pragma unroll
      for (int ww = 1; ww < 4; ++ww) {
        float v2 = part[ww][6]; int i2 = partI[ww];
        if (v2 > bv || (v2 == bv && i2 < bi)) { bv = v2; bi = i2; }
      }
      float sume2 = __fadd_rn(__fadd_rn(__fadd_rn(part[0][5], part[1][5]), part[2][5]), part[3][5]);
      out[(size_t)b*NS + step] = (float)bi;
      out[(size_t)NB*NS + (size_t)b*NS + step] = __fdiv_rn(ex2L[bi], sume2);
      xpL[0] = st0L[bi]; xpL[1] = st1L[bi];
    }
    __syncthreads();
  }
}

// ---------------- host launch ----------------
extern "C" void kernel_launch(void* const* d_in, const int* in_sizes, int n_in,
                              void* d_out, int out_size, void* d_ws, size_t ws_size,
                              hipStream_t stream) {
  (void)in_sizes; (void)n_in; (void)out_size; (void)d_ws; (void)ws_size;
  const float* stat = (const float*)d_in[0];
  const float* dyn  = (const float*)d_in[1];
  const float* sW   = (const float*)d_in[2];
  const float* sb   = (const float*)d_in[3];
  const float* dW   = (const float*)d_in[4];
  const float* db   = (const float*)d_in[5];
  const float* x0   = (const float*)d_in[6];
  const float* h0   = (const float*)d_in[7];
  const float* Wemb = (const float*)d_in[8];
  const float* bemb = (const float*)d_in[9];
  const float* Wih  = (const float*)d_in[10];
  const float* Whh  = (const float*)d_in[11];
  const float* bih  = (const float*)d_in[12];
  const float* bhh  = (const float*)d_in[13];
  const float* Wa   = (const float*)d_in[14];
  const float* va   = (const float*)d_in[15];
  const float* Wd   = (const float*)d_in[16];
  const float* vd   = (const float*)d_in[17];
  float* out = (float*)d_out;

  k_decode<<<NB, 512, 0, stream>>>(stat, dyn, sW, sb, dW, db, x0, h0,
                                   Wemb, bemb, Wih, Whh, bih, bhh,
                                   Wa, va, Wd, vd, out);
}